// Round 4
// baseline (1027.953 us; speedup 1.0000x reference)
//
#include <hip/hip_runtime.h>
#include <hip/hip_bf16.h>

#define B_ 64
#define S_ 1024
#define LOG2E 1.4426950408889634f

typedef __attribute__((ext_vector_type(8))) short bf16x8;
typedef __attribute__((ext_vector_type(4))) float f32x4;

// ---- workspace layout ----
// xw_frag : bf16 [2][4][1024][256][16] = 33,554,432 elems (64 MiB)
// bi      : bf16 [64][1024][128]       =  8,388,608 elems (16 MiB)
// u_frag  : bf16 [2][256][4][2][8]     =     32,768 elems
// mask_ws : u8   [1024][64]            =     65,536 B
// elist   : int  [15][65]              =      3,900 B
static constexpr size_t XW_ELEMS = 33554432ull;
static constexpr size_t BI_ELEMS = 8388608ull;
static constexpr size_t U_ELEMS  = 32768ull;

__device__ inline float bf2f(unsigned short u) {
    union { unsigned int i; float f; } v;
    v.i = ((unsigned int)u) << 16;
    return v.f;
}

// ---------------- K0: U -> per-lane B-fragment order, scaled by log2e ----------------
__global__ void k_uprep(const float* __restrict__ Uf, const float* __restrict__ Ub,
                        __hip_bfloat16* __restrict__ u_frag) {
    const int d = blockIdx.x;
    const float* U = d ? Ub : Uf;
    const int tid = threadIdx.x;
    const int w = tid >> 6, l = tid & 63;
    __hip_bfloat16* o = u_frag + (size_t)(d * 256 + tid) * 64;
#pragma unroll
    for (int n = 0; n < 4; ++n)
#pragma unroll
        for (int kc = 0; kc < 2; ++kc)
#pragma unroll
            for (int j = 0; j < 8; ++j) {
                const int k   = kc * 32 + ((l >> 4) << 3) + j;
                const int col = n * 64 + (w << 4) + (l & 15);
                o[(n * 2 + kc) * 8 + j] = (__hip_bfloat16)(U[k * 256 + col] * LOG2E);
            }
}

// ---------------- K0b: per-expert batch lists ----------------
__global__ void k_elist(const int* __restrict__ evt, int* __restrict__ elist) {
    const int e = threadIdx.x;
    if (e < 15) {
        int cnt = 0;
        for (int b = 0; b < 64; ++b)
            if (evt[b] == e) elist[e * 65 + 1 + (cnt++)] = b;
        elist[e * 65] = cnt;
    }
}

// ---------------- K1: xw fragments = log2e * (embed[tok] @ W + b) ----------------
__global__ __launch_bounds__(256) void k_xw(
    const int* __restrict__ inputs, const float* __restrict__ embed_table,
    const float* __restrict__ Wf, const float* __restrict__ bf_,
    const float* __restrict__ Wb, const float* __restrict__ bb_,
    __hip_bfloat16* __restrict__ xw_frag) {
    const int dir = blockIdx.y;
    const float* W    = dir ? Wb  : Wf;
    const float* bias = dir ? bb_ : bf_;
    const int bg = blockIdx.x >> 9;
    const int s0 = (blockIdx.x & 511) * 2;
    __shared__ __align__(16) float a_lds[32][128];
    const int tid = threadIdx.x;
    for (int i = tid; i < 32 * 128; i += 256) {
        const int r = i >> 7, k = i & 127;
        const int b = bg * 16 + (r & 15), s = s0 + (r >> 4);
        const int tok = inputs[b * 1024 + s];
        a_lds[r][k] = embed_table[(size_t)tok * 128 + k];
    }
    __syncthreads();
    const int g = tid;
    float acc[32];
    const float bv = bias[g];
#pragma unroll
    for (int r = 0; r < 32; ++r) acc[r] = bv;
    for (int k4 = 0; k4 < 32; ++k4) {
        const float w0 = W[(k4 * 4 + 0) * 256 + g];
        const float w1 = W[(k4 * 4 + 1) * 256 + g];
        const float w2 = W[(k4 * 4 + 2) * 256 + g];
        const float w3 = W[(k4 * 4 + 3) * 256 + g];
#pragma unroll
        for (int r = 0; r < 32; ++r) {
            const float4 av = *reinterpret_cast<const float4*>(&a_lds[r][k4 * 4]);
            acc[r] = fmaf(av.x, w0, fmaf(av.y, w1, fmaf(av.z, w2, fmaf(av.w, w3, acc[r]))));
        }
    }
    const int w = (g >> 4) & 3, n = g >> 6, c15 = g & 15;
#pragma unroll
    for (int r = 0; r < 32; ++r) {
        const int bl = r & 15, ss = s0 + (r >> 4);
        const int tid_t = w * 64 + ((bl >> 2) << 4) + c15;
        const size_t off = (((size_t)(dir * 4 + bg) * 1024 + ss) * 256 + tid_t) * 16
                         + (n * 4 + (bl & 3));
        xw_frag[off] = (__hip_bfloat16)(acc[r] * LOG2E);
    }
}

// ---------------- K2: MFMA-batched masked LSTM recurrence ----------------
// Key: raw s_barrier with lgkmcnt(0) only — vmcnt is NEVER drained in the loop,
// so xw/mask prefetch loads and bi stores stay in flight across the barrier.
__global__ __launch_bounds__(256, 1) void k_rec(
    const __hip_bfloat16* __restrict__ xw_frag,
    const __hip_bfloat16* __restrict__ u_frag,
    const unsigned char* __restrict__ mask_ws,
    __hip_bfloat16* __restrict__ bi) {
    const int bid = blockIdx.x;
    const int d = bid >> 2, bg = bid & 3;
    const int tid = threadIdx.x, w = tid >> 6, l = tid & 63;

    bf16x8 bfr[4][2];
    {
        const bf16x8* up = (const bf16x8*)(u_frag + (size_t)(d * 256 + tid) * 64);
#pragma unroll
        for (int n = 0; n < 4; ++n)
#pragma unroll
            for (int kc = 0; kc < 2; ++kc) bfr[n][kc] = up[n * 2 + kc];
    }

    __shared__ __align__(16) unsigned short hbuf[2][1024];
    for (int i = tid; i < 2048; i += 256) hbuf[0][i] = 0;
    __syncthreads();

    const int arow = l & 15;
    const int sw = ((arow >> 2) & 3) << 1;
    const int aoff0 = arow * 128 + (((l >> 4)     ^ sw) & 7) * 16;
    const int aoff1 = arow * 128 + (((4 + (l >> 4)) ^ sw) & 7) * 16;
    const int wch = ((2 * w + ((l & 15) >> 3)) ^ ((l >> 4) << 1)) & 7;
    const int woffbase = (l >> 4) * 512 + wch * 16 + (l & 7) * 2;

    unsigned short* bi_u = (unsigned short*)bi;
    size_t bioff[4];
#pragma unroll
    for (int r = 0; r < 4; ++r)
        bioff[r] = (size_t)(bg * 16 + 4 * (l >> 4) + r) * 1024 * 128
                 + d * 64 + 16 * w + (l & 15);

    float c_st[4] = {0.f, 0.f, 0.f, 0.f};
    float h_st[4] = {0.f, 0.f, 0.f, 0.f};

    const size_t xwbase = (size_t)(d * 4 + bg) * 1024;
    const char* xbase = (const char*)(xw_frag + (xwbase * 256 + tid) * 16);  // + time*8192
    const unsigned char* mbase = mask_ws + ((l >> 4) << 2);                  // + time*64

    // 4-deep register pipeline
    uint4 pxa[4], pxb[4];
    unsigned int pm[4];
#pragma unroll
    for (int j = 0; j < 4; ++j) {
        const int time = d ? 1023 - j : j;
        const uint4* xp = (const uint4*)(xbase + (size_t)time * 8192);
        pxa[j] = xp[0]; pxb[j] = xp[1];
        pm[j] = *(const unsigned int*)(mbase + time * 64);
    }

    for (int tb = 0; tb < 1024; tb += 4) {
#pragma unroll
        for (int j = 0; j < 4; ++j) {
            const int t = tb + j;
            const int time = d ? 1023 - t : t;
            const uint4 cxa = pxa[j], cxb = pxb[j];
            const unsigned int cm4 = pm[j];
            // prefetch t+4 (clamped reload at tail; values unused)
            {
                const int tn = (t + 4 < 1024) ? (t + 4) : t;
                const int timen = d ? 1023 - tn : tn;
                const uint4* np = (const uint4*)(xbase + (size_t)timen * 8192);
                pxa[j] = np[0]; pxb[j] = np[1];
                pm[j] = *(const unsigned int*)(mbase + timen * 64);
            }
            const char* hb = (const char*)(hbuf[0] + (t & 1) * 1024);
            const bf16x8 a0 = *(const bf16x8*)(hb + aoff0);
            const bf16x8 a1 = *(const bf16x8*)(hb + aoff1);
            float z[16];
            {
                const unsigned int du[8] = {cxa.x, cxa.y, cxa.z, cxa.w,
                                            cxb.x, cxb.y, cxb.z, cxb.w};
#pragma unroll
                for (int q = 0; q < 8; ++q) {
                    z[2 * q]     = __builtin_bit_cast(float, du[q] << 16);
                    z[2 * q + 1] = __builtin_bit_cast(float, du[q] & 0xffff0000u);
                }
            }
            f32x4 acc[4];
#pragma unroll
            for (int n = 0; n < 4; ++n) {
                f32x4 ci = {z[n * 4 + 0], z[n * 4 + 1], z[n * 4 + 2], z[n * 4 + 3]};
                ci = __builtin_amdgcn_mfma_f32_16x16x32_bf16(a0, bfr[n][0], ci, 0, 0, 0);
                acc[n] = __builtin_amdgcn_mfma_f32_16x16x32_bf16(a1, bfr[n][1], ci, 0, 0, 0);
            }
            unsigned short* hw = hbuf[0] + ((t + 1) & 1) * 1024;
#pragma unroll
            for (int r = 0; r < 4; ++r) {
                const float zi = acc[0][r], zf = acc[1][r], zg = acc[2][r], zo = acc[3][r];
                const float iv = __builtin_amdgcn_rcpf(1.f + __builtin_amdgcn_exp2f(-zi));
                const float fv = __builtin_amdgcn_rcpf(1.f + __builtin_amdgcn_exp2f(-zf));
                const float ov = __builtin_amdgcn_rcpf(1.f + __builtin_amdgcn_exp2f(-zo));
                const float eg = __builtin_amdgcn_exp2f(-2.f * zg);
                const float tg = (1.f - eg) * __builtin_amdgcn_rcpf(1.f + eg);
                const float cn = fv * c_st[r] + iv * tg;
                const float e2 = __builtin_amdgcn_exp2f(-2.f * LOG2E * cn);
                const float th = (1.f - e2) * __builtin_amdgcn_rcpf(1.f + e2);
                const float hn = ov * th;
                const bool m = (cm4 >> (r * 8)) & 1u;
                const float h2 = m ? hn : h_st[r];
                c_st[r] = m ? cn : c_st[r];
                h_st[r] = h2;
                const unsigned short hb16 = __builtin_bit_cast(unsigned short, (__hip_bfloat16)h2);
                hw[(woffbase + r * 128) >> 1] = hb16;
                bi_u[bioff[r] + (size_t)time * 128] = hb16;
            }
            // LDS-only fence + raw barrier: do NOT drain vmcnt (prefetches/stores
            // stay in flight). "memory" clobber pins LDS ops on the right side.
            asm volatile("s_waitcnt lgkmcnt(0)" ::: "memory");
            __builtin_amdgcn_s_barrier();
        }
    }
}

// ---------------- K3: event_logits ----------------
__global__ __launch_bounds__(1024) void k_logits(
    const __hip_bfloat16* __restrict__ bi, const float* __restrict__ Wt,
    const float* __restrict__ bt, float* __restrict__ out) {
    const int tid = threadIdx.x;
    const int b = tid >> 4, cls = tid & 15;
    const __hip_bfloat16* row = bi + ((size_t)b * S_ + (S_ - 1)) * 128;
    float acc = bt[cls];
    for (int k = 0; k < 128; ++k)
        acc = fmaf((float)row[k], Wt[k * 16 + cls], acc);
    out[tid] = 1.f / (1.f + __expf(-acc));
}

// ---------------- K4: expert-dedup einsum, list-driven scatter ----------------
__global__ __launch_bounds__(256) void k_args(
    const __hip_bfloat16* __restrict__ bi,
    const float* __restrict__ ev_table, const int* __restrict__ evt,
    const float* __restrict__ W_arg, const float* __restrict__ b_arg,
    const int* __restrict__ elist,
    float* __restrict__ out_args) {
    const int e = blockIdx.x;
    const int cnt = elist[e * 65];
    if (cnt == 0) return;
    const int rowbase = blockIdx.y * 64;
    const int cc = rowbase >> 10;
    __shared__ float feat[64][169];
    __shared__ __align__(16) float w[1280];
    __shared__ float partial[4][64][8];
    __shared__ int   bl_l[64];
    __shared__ float bg[8];
    const int tid = threadIdx.x;
    for (int i = tid; i < 1280; i += 256) w[i] = W_arg[(size_t)e * 1280 + i];
    if (tid < cnt) bl_l[tid] = elist[e * 65 + 1 + tid];
    if (tid < 8)  bg[tid] = b_arg[e * 8 + tid];
    const ushort2* bi2 = reinterpret_cast<const ushort2*>(bi) + (size_t)rowbase * 64;
    for (int i = tid; i < 64 * 64; i += 256) {
        const int r = i >> 6, k2 = i & 63;
        const ushort2 v = bi2[(size_t)r * 64 + k2];
        feat[r][k2 * 2]     = bf2f(v.x);
        feat[r][k2 * 2 + 1] = bf2f(v.y);
    }
    {
        const int ie = evt[cc];
        const float* evrow = ev_table + (size_t)ie * 32;
        for (int i = tid; i < 64 * 32; i += 256) {
            const int r = i >> 5, k = i & 31;
            feat[r][128 + k] = evrow[k];
        }
    }
    __syncthreads();
    const int r = tid & 63, seg = tid >> 6;
    float acc[8];
#pragma unroll
    for (int a = 0; a < 8; ++a) acc[a] = 0.f;
    const int f0 = seg * 40;
    for (int f = f0; f < f0 + 40; ++f) {
        const float fv = feat[r][f];
        const float4 w0 = *reinterpret_cast<const float4*>(&w[f * 8]);
        const float4 w1 = *reinterpret_cast<const float4*>(&w[f * 8 + 4]);
        acc[0] = fmaf(fv, w0.x, acc[0]);
        acc[1] = fmaf(fv, w0.y, acc[1]);
        acc[2] = fmaf(fv, w0.z, acc[2]);
        acc[3] = fmaf(fv, w0.w, acc[3]);
        acc[4] = fmaf(fv, w1.x, acc[4]);
        acc[5] = fmaf(fv, w1.y, acc[5]);
        acc[6] = fmaf(fv, w1.z, acc[6]);
        acc[7] = fmaf(fv, w1.w, acc[7]);
    }
#pragma unroll
    for (int a = 0; a < 8; ++a) partial[seg][r][a] = acc[a];
    __syncthreads();
    for (int o = tid; o < 512; o += 256) {
        const int rr = o >> 3, a = o & 7;
        const float v = bg[a] + partial[0][rr][a] + partial[1][rr][a]
                              + partial[2][rr][a] + partial[3][rr][a];
        const size_t base = ((size_t)(rowbase + rr)) * 8 + a;
        for (int j = 0; j < cnt; ++j)
            out_args[((size_t)bl_l[j] << 19) + base] = v;
    }
}

// ---------------- K5: mask ----------------
__global__ __launch_bounds__(256) void k_mask(const int* __restrict__ inputs,
                                              float* __restrict__ om,
                                              unsigned char* __restrict__ mws) {
    const int i = blockIdx.x * 256 + threadIdx.x;
    const int b = i >> 10, s = i & 1023;
    const int nz = (inputs[i] != 0) ? 1 : 0;
    om[i] = (float)nz;
    mws[s * 64 + b] = (unsigned char)nz;
}

extern "C" void kernel_launch(void* const* d_in, const int* in_sizes, int n_in,
                              void* d_out, int out_size, void* d_ws, size_t ws_size,
                              hipStream_t stream) {
    const int*   inputs = (const int*)d_in[0];
    const int*   evt    = (const int*)d_in[1];
    const float* embed  = (const float*)d_in[2];
    const float* Wf     = (const float*)d_in[3];
    const float* Uf     = (const float*)d_in[4];
    const float* bf_    = (const float*)d_in[5];
    const float* Wb     = (const float*)d_in[6];
    const float* Ub     = (const float*)d_in[7];
    const float* bb_    = (const float*)d_in[8];
    const float* evtab  = (const float*)d_in[9];
    const float* Wt     = (const float*)d_in[10];
    const float* bt     = (const float*)d_in[11];
    const float* W_arg  = (const float*)d_in[12];
    const float* b_arg  = (const float*)d_in[13];

    float* out        = (float*)d_out;
    float* out_logits = out;
    float* out_args   = out + 1024;
    float* out_mask   = out + 1024 + 33554432;

    __hip_bfloat16* xw_frag = (__hip_bfloat16*)d_ws;
    __hip_bfloat16* bi      = xw_frag + XW_ELEMS;
    __hip_bfloat16* u_frag  = bi + BI_ELEMS;
    unsigned char*  mask_ws = (unsigned char*)(u_frag + U_ELEMS);
    int*            elist   = (int*)(mask_ws + 65536);

    k_uprep <<<dim3(2),        256, 0, stream>>>(Uf, Ub, u_frag);
    k_elist <<<dim3(1),         64, 0, stream>>>(evt, elist);
    k_mask  <<<dim3(256),      256, 0, stream>>>(inputs, out_mask, mask_ws);
    k_xw    <<<dim3(2048, 2),  256, 0, stream>>>(inputs, embed, Wf, bf_, Wb, bb_, xw_frag);
    k_rec   <<<dim3(8),        256, 0, stream>>>(xw_frag, u_frag, mask_ws, bi);
    k_logits<<<dim3(1),       1024, 0, stream>>>(bi, Wt, bt, out_logits);
    k_args  <<<dim3(15, 1024), 256, 0, stream>>>(bi, evtab, evt, W_arg, b_arg, elist, out_args);
}

// Round 5
// 921.807 us; speedup vs baseline: 1.1151x; 1.1151x over previous
//
#include <hip/hip_runtime.h>
#include <hip/hip_bf16.h>

#define B_ 64
#define S_ 1024
#define LOG2E 1.4426950408889634f

typedef __attribute__((ext_vector_type(8))) short bf16x8;
typedef __attribute__((ext_vector_type(4))) float f32x4;

// ---- workspace layout ----
// xw_frag : bf16 [2][4][1024][4][64][16] = 33,554,432 elems (64 MiB)
//           per (dir,bg,time): [cslice(4)][lane(64)][reg(4)*4+n]
// bi_t    : bf16 [64][128][1024]         =  8,388,608 elems (16 MiB)  (transposed!)
// u_frag  : bf16 [2][4][64][4][2][8]     =     32,768 elems
// mask_ws : u8   [1024][64]              =     65,536 B
// elist   : int  [15][65]
static constexpr size_t XW_ELEMS = 33554432ull;
static constexpr size_t BI_ELEMS = 8388608ull;
static constexpr size_t U_ELEMS  = 32768ull;

__device__ inline float bf2f(unsigned short u) {
    union { unsigned int i; float f; } v;
    v.i = ((unsigned int)u) << 16;
    return v.f;
}

// ---------------- K0: U -> per-lane B-fragment order, scaled by log2e ----------------
__global__ void k_uprep(const float* __restrict__ Uf, const float* __restrict__ Ub,
                        __hip_bfloat16* __restrict__ u_frag) {
    const int d = blockIdx.x;
    const float* U = d ? Ub : Uf;
    const int tid = threadIdx.x;
    const int w = tid >> 6, l = tid & 63;
    __hip_bfloat16* o = u_frag + (size_t)(d * 256 + tid) * 64;
#pragma unroll
    for (int n = 0; n < 4; ++n)
#pragma unroll
        for (int kc = 0; kc < 2; ++kc)
#pragma unroll
            for (int j = 0; j < 8; ++j) {
                const int k   = kc * 32 + ((l >> 4) << 3) + j;
                const int col = n * 64 + (w << 4) + (l & 15);
                o[(n * 2 + kc) * 8 + j] = (__hip_bfloat16)(U[k * 256 + col] * LOG2E);
            }
}

// ---------------- K0b: per-expert batch lists ----------------
__global__ void k_elist(const int* __restrict__ evt, int* __restrict__ elist) {
    const int e = threadIdx.x;
    if (e < 15) {
        int cnt = 0;
        for (int b = 0; b < 64; ++b)
            if (evt[b] == e) elist[e * 65 + 1 + (cnt++)] = b;
        elist[e * 65] = cnt;
    }
}

// ---------------- K1: xw fragments = log2e * (embed[tok] @ W + b) ----------------
__global__ __launch_bounds__(256) void k_xw(
    const int* __restrict__ inputs, const float* __restrict__ embed_table,
    const float* __restrict__ Wf, const float* __restrict__ bf_,
    const float* __restrict__ Wb, const float* __restrict__ bb_,
    __hip_bfloat16* __restrict__ xw_frag) {
    const int dir = blockIdx.y;
    const float* W    = dir ? Wb  : Wf;
    const float* bias = dir ? bb_ : bf_;
    const int bg = blockIdx.x >> 9;
    const int s0 = (blockIdx.x & 511) * 2;
    __shared__ __align__(16) float a_lds[32][128];
    const int tid = threadIdx.x;
    for (int i = tid; i < 32 * 128; i += 256) {
        const int r = i >> 7, k = i & 127;
        const int b = bg * 16 + (r & 15), s = s0 + (r >> 4);
        const int tok = inputs[b * 1024 + s];
        a_lds[r][k] = embed_table[(size_t)tok * 128 + k];
    }
    __syncthreads();
    const int g = tid;
    float acc[32];
    const float bv = bias[g];
#pragma unroll
    for (int r = 0; r < 32; ++r) acc[r] = bv;
    for (int k4 = 0; k4 < 32; ++k4) {
        const float w0 = W[(k4 * 4 + 0) * 256 + g];
        const float w1 = W[(k4 * 4 + 1) * 256 + g];
        const float w2 = W[(k4 * 4 + 2) * 256 + g];
        const float w3 = W[(k4 * 4 + 3) * 256 + g];
#pragma unroll
        for (int r = 0; r < 32; ++r) {
            const float4 av = *reinterpret_cast<const float4*>(&a_lds[r][k4 * 4]);
            acc[r] = fmaf(av.x, w0, fmaf(av.y, w1, fmaf(av.z, w2, fmaf(av.w, w3, acc[r]))));
        }
    }
    // scatter to fragment layout: [cslice][lane][reg*4+n]
    const int n = g >> 6, cw = (g >> 4) & 3, c15 = g & 15;
#pragma unroll
    for (int r = 0; r < 32; ++r) {
        const int bl = r & 15, ss = s0 + (r >> 4);
        const int lane = ((bl >> 2) << 4) + c15;
        const size_t off = ((((size_t)(dir * 4 + bg) * 1024 + ss) * 4 + cw) * 64 + lane) * 16
                         + (bl & 3) * 4 + n;
        xw_frag[off] = (__hip_bfloat16)(acc[r] * LOG2E);
    }
}

// ---------------- K2: MFMA-batched masked LSTM recurrence ----------------
// 8 blocks x 512 threads (8 waves = 2/SIMD). Wave (cw=wf>>1, p=wf&1): cols
// [16cw,16cw+16) of each gate; MFMA duplicated within the pair; activation
// split by acc-reg half (p=0 -> regs 0,1 ; p=1 -> regs 2,3).
__global__ __launch_bounds__(512, 1) void k_rec(
    const __hip_bfloat16* __restrict__ xw_frag,
    const __hip_bfloat16* __restrict__ u_frag,
    const unsigned char* __restrict__ mask_ws,
    __hip_bfloat16* __restrict__ bi_t) {
    const int bid = blockIdx.x;
    const int d = bid >> 2, bg = bid & 3;
    const int tid = threadIdx.x, wf = tid >> 6, l = tid & 63;
    const int cw = wf >> 1, p = wf & 1;

    bf16x8 bfr[4][2];
    {
        const bf16x8* up = (const bf16x8*)(u_frag + (size_t)(d * 256 + cw * 64 + l) * 64);
#pragma unroll
        for (int n = 0; n < 4; ++n)
#pragma unroll
            for (int kc = 0; kc < 2; ++kc) bfr[n][kc] = up[n * 2 + kc];
    }

    __shared__ __align__(16) unsigned short hbuf[2][1024];
    for (int i = tid; i < 2048; i += 512) hbuf[0][i] = 0;
    __syncthreads();

    // A-frag read byte offsets (lane-only, same as verified R2 layout)
    const int arow = l & 15;
    const int sw = ((arow >> 2) & 3) << 1;
    const int aoff0 = arow * 128 + (((l >> 4)     ^ sw) & 7) * 16;
    const int aoff1 = arow * 128 + (((4 + (l >> 4)) ^ sw) & 7) * 16;
    // h-write offsets for regs 2p, 2p+1
    const int wch = ((2 * cw + ((l & 15) >> 3)) ^ ((l >> 4) << 1)) & 7;
    const int base_w = (l >> 4) * 512 + wch * 16 + (l & 7) * 2;
    const int woff0 = base_w + (2 * p + 0) * 128;
    const int woff1 = base_w + (2 * p + 1) * 128;

    unsigned short* bt_u = (unsigned short*)bi_t;
    const size_t bt0 = ((size_t)((bg * 16 + 4 * (l >> 4) + 2 * p) * 128
                                 + d * 64 + 16 * cw + (l & 15))) << 10;
    const size_t bt1 = bt0 + (128ull << 10);

    float c_st0 = 0.f, c_st1 = 0.f, h_st0 = 0.f, h_st1 = 0.f;

    const char* xbase = (const char*)xw_frag
                      + ((size_t)(d * 4 + bg) * 1024) * 8192 + (cw * 64 + l) * 32 + p * 16;
    const unsigned char* mbase = mask_ws + ((l >> 4) << 2);

    // 2-deep prefetch
    uint4 px[2]; unsigned int pmk[2];
#pragma unroll
    for (int j = 0; j < 2; ++j) {
        const int time = d ? 1023 - j : j;
        px[j]  = *(const uint4*)(xbase + (size_t)time * 8192);
        pmk[j] = *(const unsigned int*)(mbase + time * 64);
    }

    unsigned short h4a[4], h4b[4];
    const int shift0 = 16 * p;           // mask bit shifts
    const int shift1 = 16 * p + 8;

    for (int tb = 0; tb < 1024; tb += 4) {
#pragma unroll
        for (int j = 0; j < 4; ++j) {
            const int t = tb + j;
            const uint4 cx = px[j & 1];
            const unsigned int cm = pmk[j & 1];
            {   // prefetch t+2
                const int tn = (t + 2 < 1024) ? t + 2 : 1023;
                const int timen = d ? 1023 - tn : tn;
                px[j & 1]  = *(const uint4*)(xbase + (size_t)timen * 8192);
                pmk[j & 1] = *(const unsigned int*)(mbase + timen * 64);
            }
            const char* hb = (const char*)(hbuf[0] + (t & 1) * 1024);
            const bf16x8 a0 = *(const bf16x8*)(hb + aoff0);
            const bf16x8 a1 = *(const bf16x8*)(hb + aoff1);
            // unpack 8 z values: slot = rl*4 + n
            float z[8];
            {
                const unsigned int du[4] = {cx.x, cx.y, cx.z, cx.w};
#pragma unroll
                for (int q = 0; q < 4; ++q) {
                    z[2 * q]     = __builtin_bit_cast(float, du[q] << 16);
                    z[2 * q + 1] = __builtin_bit_cast(float, du[q] & 0xffff0000u);
                }
            }
            f32x4 acc[4];
#pragma unroll
            for (int n = 0; n < 4; ++n) {
                f32x4 ci = {z[n], z[4 + n], z[n], z[4 + n]};  // valid at regs {2p,2p+1}
                ci = __builtin_amdgcn_mfma_f32_16x16x32_bf16(a0, bfr[n][0], ci, 0, 0, 0);
                acc[n] = __builtin_amdgcn_mfma_f32_16x16x32_bf16(a1, bfr[n][1], ci, 0, 0, 0);
            }
            unsigned short* hw = hbuf[0] + ((t + 1) & 1) * 1024;
#pragma unroll
            for (int rl = 0; rl < 2; ++rl) {
                const float zi = p ? acc[0][2 + rl] : acc[0][rl];
                const float zf = p ? acc[1][2 + rl] : acc[1][rl];
                const float zg = p ? acc[2][2 + rl] : acc[2][rl];
                const float zo = p ? acc[3][2 + rl] : acc[3][rl];
                const float c_st = rl ? c_st1 : c_st0;
                const float h_st = rl ? h_st1 : h_st0;
                const float iv = __builtin_amdgcn_rcpf(1.f + __builtin_amdgcn_exp2f(-zi));
                const float fv = __builtin_amdgcn_rcpf(1.f + __builtin_amdgcn_exp2f(-zf));
                const float ov = __builtin_amdgcn_rcpf(1.f + __builtin_amdgcn_exp2f(-zo));
                const float eg = __builtin_amdgcn_exp2f(-2.f * zg);
                const float tg = (1.f - eg) * __builtin_amdgcn_rcpf(1.f + eg);
                const float cn = fv * c_st + iv * tg;
                const float e2 = __builtin_amdgcn_exp2f(-2.f * LOG2E * cn);
                const float th = (1.f - e2) * __builtin_amdgcn_rcpf(1.f + e2);
                const float hn = ov * th;
                const bool m = (cm >> (rl ? shift1 : shift0)) & 1u;
                const float h2 = m ? hn : h_st;
                if (rl) { c_st1 = m ? cn : c_st1; h_st1 = h2; }
                else    { c_st0 = m ? cn : c_st0; h_st0 = h2; }
                const unsigned short hb16 =
                    __builtin_bit_cast(unsigned short, (__hip_bfloat16)h2);
                *(unsigned short*)((char*)hw + (rl ? woff1 : woff0)) = hb16;
                if (rl) h4b[j] = hb16; else h4a[j] = hb16;
            }
            if (j == 3) {   // flush 4 packed timesteps to bi_t
                uint2 ua, ub;
                int stime;
                if (d == 0) {
                    ua.x = (unsigned int)h4a[0] | ((unsigned int)h4a[1] << 16);
                    ua.y = (unsigned int)h4a[2] | ((unsigned int)h4a[3] << 16);
                    ub.x = (unsigned int)h4b[0] | ((unsigned int)h4b[1] << 16);
                    ub.y = (unsigned int)h4b[2] | ((unsigned int)h4b[3] << 16);
                    stime = tb;
                } else {
                    ua.x = (unsigned int)h4a[3] | ((unsigned int)h4a[2] << 16);
                    ua.y = (unsigned int)h4a[1] | ((unsigned int)h4a[0] << 16);
                    ub.x = (unsigned int)h4b[3] | ((unsigned int)h4b[2] << 16);
                    ub.y = (unsigned int)h4b[1] | ((unsigned int)h4b[0] << 16);
                    stime = 1020 - tb;
                }
                *(uint2*)(bt_u + bt0 + stime) = ua;
                *(uint2*)(bt_u + bt1 + stime) = ub;
            }
            asm volatile("s_waitcnt lgkmcnt(0)" ::: "memory");
            __builtin_amdgcn_s_barrier();
        }
    }
}

// ---------------- K3: event_logits (reads transposed bi_t) ----------------
__global__ __launch_bounds__(1024) void k_logits(
    const __hip_bfloat16* __restrict__ bi_t, const float* __restrict__ Wt,
    const float* __restrict__ bt, float* __restrict__ out) {
    const int tid = threadIdx.x;
    const int b = tid >> 4, cls = tid & 15;
    const unsigned short* btu = (const unsigned short*)bi_t;
    float acc = bt[cls];
    for (int k = 0; k < 128; ++k)
        acc = fmaf(bf2f(btu[(((size_t)b * 128 + k) << 10) + 1023]), Wt[k * 16 + cls], acc);
    out[tid] = 1.f / (1.f + __expf(-acc));
}

// ---------------- K4: expert-dedup einsum, list-driven scatter ----------------
__global__ __launch_bounds__(256) void k_args(
    const __hip_bfloat16* __restrict__ bi_t,
    const float* __restrict__ ev_table, const int* __restrict__ evt,
    const float* __restrict__ W_arg, const float* __restrict__ b_arg,
    const int* __restrict__ elist,
    float* __restrict__ out_args) {
    const int e = blockIdx.x;
    const int cnt = elist[e * 65];
    if (cnt == 0) return;
    const int rowbase = blockIdx.y * 64;
    const int cc = rowbase >> 10, sbase = rowbase & 1023;
    __shared__ float feat[64][169];
    __shared__ __align__(16) float w[1280];
    __shared__ float partial[4][64][8];
    __shared__ int   bl_l[64];
    __shared__ float bg[8];
    const int tid = threadIdx.x;
    for (int i = tid; i < 1280; i += 256) w[i] = W_arg[(size_t)e * 1280 + i];
    if (tid < cnt) bl_l[tid] = elist[e * 65 + 1 + tid];
    if (tid < 8)  bg[tid] = b_arg[e * 8 + tid];
    const unsigned short* btu = (const unsigned short*)bi_t;
    for (int i = tid; i < 64 * 128; i += 256) {
        const int k = i >> 6, r = i & 63;
        feat[r][k] = bf2f(btu[(((size_t)cc * 128 + k) << 10) + sbase + r]);
    }
    {
        const int ie = evt[cc];
        const float* evrow = ev_table + (size_t)ie * 32;
        for (int i = tid; i < 64 * 32; i += 256) {
            const int r = i >> 5, k = i & 31;
            feat[r][128 + k] = evrow[k];
        }
    }
    __syncthreads();
    const int r = tid & 63, seg = tid >> 6;
    float acc[8];
#pragma unroll
    for (int a = 0; a < 8; ++a) acc[a] = 0.f;
    const int f0 = seg * 40;
    for (int f = f0; f < f0 + 40; ++f) {
        const float fv = feat[r][f];
        const float4 w0 = *reinterpret_cast<const float4*>(&w[f * 8]);
        const float4 w1 = *reinterpret_cast<const float4*>(&w[f * 8 + 4]);
        acc[0] = fmaf(fv, w0.x, acc[0]);
        acc[1] = fmaf(fv, w0.y, acc[1]);
        acc[2] = fmaf(fv, w0.z, acc[2]);
        acc[3] = fmaf(fv, w0.w, acc[3]);
        acc[4] = fmaf(fv, w1.x, acc[4]);
        acc[5] = fmaf(fv, w1.y, acc[5]);
        acc[6] = fmaf(fv, w1.z, acc[6]);
        acc[7] = fmaf(fv, w1.w, acc[7]);
    }
#pragma unroll
    for (int a = 0; a < 8; ++a) partial[seg][r][a] = acc[a];
    __syncthreads();
    for (int o = tid; o < 512; o += 256) {
        const int rr = o >> 3, a = o & 7;
        const float v = bg[a] + partial[0][rr][a] + partial[1][rr][a]
                              + partial[2][rr][a] + partial[3][rr][a];
        const size_t base = ((size_t)(rowbase + rr)) * 8 + a;
        for (int j = 0; j < cnt; ++j)
            out_args[((size_t)bl_l[j] << 19) + base] = v;
    }
}

// ---------------- K5: mask ----------------
__global__ __launch_bounds__(256) void k_mask(const int* __restrict__ inputs,
                                              float* __restrict__ om,
                                              unsigned char* __restrict__ mws) {
    const int i = blockIdx.x * 256 + threadIdx.x;
    const int b = i >> 10, s = i & 1023;
    const int nz = (inputs[i] != 0) ? 1 : 0;
    om[i] = (float)nz;
    mws[s * 64 + b] = (unsigned char)nz;
}

extern "C" void kernel_launch(void* const* d_in, const int* in_sizes, int n_in,
                              void* d_out, int out_size, void* d_ws, size_t ws_size,
                              hipStream_t stream) {
    const int*   inputs = (const int*)d_in[0];
    const int*   evt    = (const int*)d_in[1];
    const float* embed  = (const float*)d_in[2];
    const float* Wf     = (const float*)d_in[3];
    const float* Uf     = (const float*)d_in[4];
    const float* bf_    = (const float*)d_in[5];
    const float* Wb     = (const float*)d_in[6];
    const float* Ub     = (const float*)d_in[7];
    const float* bb_    = (const float*)d_in[8];
    const float* evtab  = (const float*)d_in[9];
    const float* Wt     = (const float*)d_in[10];
    const float* bt     = (const float*)d_in[11];
    const float* W_arg  = (const float*)d_in[12];
    const float* b_arg  = (const float*)d_in[13];

    float* out        = (float*)d_out;
    float* out_logits = out;
    float* out_args   = out + 1024;
    float* out_mask   = out + 1024 + 33554432;

    __hip_bfloat16* xw_frag = (__hip_bfloat16*)d_ws;
    __hip_bfloat16* bi_t    = xw_frag + XW_ELEMS;
    __hip_bfloat16* u_frag  = bi_t + BI_ELEMS;
    unsigned char*  mask_ws = (unsigned char*)(u_frag + U_ELEMS);
    int*            elist   = (int*)(mask_ws + 65536);

    k_uprep <<<dim3(2),        256, 0, stream>>>(Uf, Ub, u_frag);
    k_elist <<<dim3(1),         64, 0, stream>>>(evt, elist);
    k_mask  <<<dim3(256),      256, 0, stream>>>(inputs, out_mask, mask_ws);
    k_xw    <<<dim3(2048, 2),  256, 0, stream>>>(inputs, embed, Wf, bf_, Wb, bb_, xw_frag);
    k_rec   <<<dim3(8),        512, 0, stream>>>(xw_frag, u_frag, mask_ws, bi_t);
    k_logits<<<dim3(1),       1024, 0, stream>>>(bi_t, Wt, bt, out_logits);
    k_args  <<<dim3(15, 1024), 256, 0, stream>>>(bi_t, evtab, evt, W_arg, b_arg, elist, out_args);
}

// Round 6
// 777.115 us; speedup vs baseline: 1.3228x; 1.1862x over previous
//
#include <hip/hip_runtime.h>
#include <hip/hip_bf16.h>

#define B_ 64
#define S_ 1024
#define LOG2E 1.4426950408889634f

typedef __attribute__((ext_vector_type(8))) short bf16x8;
typedef __attribute__((ext_vector_type(4))) float f32x4;

// ---- workspace layout ----
// xw_frag : bf16 [2][4][1024][4][64][16] = 33,554,432 elems (64 MiB)
//           per (dir,bg,time): [cslice(4)][lane(64)][reg(4)*4+gate(4)]   (UNSCALED z)
// bi_t    : bf16 [64][128][1024]         =  8,388,608 elems (16 MiB)  (transposed)
// u_frag  : bf16 [2][4][64][4][2][8]     =     32,768 elems (unscaled)
// w_frag  : bf16 [2][4][64][4][4][8]     =     65,536 elems
// mask_ws : u8   [1024][64]              =     65,536 B
// elist   : int  [15][65]
static constexpr size_t XW_ELEMS = 33554432ull;
static constexpr size_t BI_ELEMS = 8388608ull;
static constexpr size_t U_ELEMS  = 32768ull;
static constexpr size_t W_ELEMS  = 65536ull;

__device__ inline float bf2f(unsigned short u) {
    union { unsigned int i; float f; } v;
    v.i = ((unsigned int)u) << 16;
    return v.f;
}
__device__ inline unsigned short f2bf(float f) {
    return __builtin_bit_cast(unsigned short, (__hip_bfloat16)f);
}
__device__ inline float sig_exact(float z) {
    return __builtin_amdgcn_rcpf(1.f + __builtin_amdgcn_exp2f(-z * LOG2E));
}
__device__ inline float tanh_exact(float z) {
    const float e = __builtin_amdgcn_exp2f(-2.f * LOG2E * z);
    return (1.f - e) * __builtin_amdgcn_rcpf(1.f + e);
}

// ---------------- K0: U -> per-lane B-fragment order (unscaled) ----------------
__global__ void k_uprep(const float* __restrict__ Uf, const float* __restrict__ Ub,
                        __hip_bfloat16* __restrict__ u_frag) {
    const int d = blockIdx.x;
    const float* U = d ? Ub : Uf;
    const int tid = threadIdx.x;
    const int w = tid >> 6, l = tid & 63;
    __hip_bfloat16* o = u_frag + (size_t)(d * 256 + tid) * 64;
#pragma unroll
    for (int n = 0; n < 4; ++n)
#pragma unroll
        for (int kc = 0; kc < 2; ++kc)
#pragma unroll
            for (int j = 0; j < 8; ++j) {
                const int k   = kc * 32 + ((l >> 4) << 3) + j;
                const int col = n * 64 + (w << 4) + (l & 15);
                o[(n * 2 + kc) * 8 + j] = (__hip_bfloat16)U[k * 256 + col];
            }
}

// ---------------- K0c: W -> per-lane B-fragment order for k_xw ----------------
__global__ void k_wprep(const float* __restrict__ Wf, const float* __restrict__ Wb,
                        __hip_bfloat16* __restrict__ w_frag) {
    const int dir = blockIdx.x;
    const float* W = dir ? Wb : Wf;
    const int tid = threadIdx.x;
    const int cw = tid >> 6, l = tid & 63;
    __hip_bfloat16* o = w_frag + (((size_t)dir * 4 + cw) * 64 + l) * 128;
#pragma unroll
    for (int n = 0; n < 4; ++n)
#pragma unroll
        for (int ks = 0; ks < 4; ++ks)
#pragma unroll
            for (int j = 0; j < 8; ++j) {
                const int k   = ks * 32 + ((l >> 4) << 3) + j;
                const int col = n * 64 + cw * 16 + (l & 15);
                o[(n * 4 + ks) * 8 + j] = (__hip_bfloat16)W[k * 256 + col];
            }
}

// ---------------- K0b: per-expert batch lists ----------------
__global__ void k_elist(const int* __restrict__ evt, int* __restrict__ elist) {
    const int e = threadIdx.x;
    if (e < 15) {
        int cnt = 0;
        for (int b = 0; b < 64; ++b)
            if (evt[b] == e) elist[e * 65 + 1 + (cnt++)] = b;
        elist[e * 65] = cnt;
    }
}

// ---------------- K1: xw fragments via MFMA: z = embed[tok] @ W + b ----------------
// grid (128, 8): x = time-tile (8 steps), y = dir*4+bg. 4 waves, wave = cslice.
__global__ __launch_bounds__(256, 4) void k_xw(
    const int* __restrict__ inputs, const float* __restrict__ embed_table,
    const float* __restrict__ bf_, const float* __restrict__ bb_,
    const __hip_bfloat16* __restrict__ w_frag,
    __hip_bfloat16* __restrict__ xw_frag) {
    const int dbg = blockIdx.y, dir = dbg >> 2;
    const float* bias = dir ? bb_ : bf_;
    const int t0 = blockIdx.x * 8;
    const int tid = threadIdx.x, cw = tid >> 6, l = tid & 63;

    bf16x8 wf[4][4];   // [gate n][kstep]
    {
        const bf16x8* wp = (const bf16x8*)(w_frag + (((size_t)dir * 4 + cw) * 64 + l) * 128);
#pragma unroll
        for (int n = 0; n < 4; ++n)
#pragma unroll
            for (int ks = 0; ks < 4; ++ks) wf[n][ks] = wp[n * 4 + ks];
    }
    float bv[4];
#pragma unroll
    for (int n = 0; n < 4; ++n) bv[n] = bias[n * 64 + cw * 16 + (l & 15)];

    const int b = (dbg & 3) * 16 + (l & 15);   // A row = batch
    const int krow = (l >> 4) * 8;
    const int* tokp = inputs + b * 1024 + t0;

    for (int tt = 0; tt < 8; ++tt) {
        const int tok = tokp[tt];
        const float* er = embed_table + (size_t)tok * 128 + krow;
        bf16x8 af[4];
#pragma unroll
        for (int ks = 0; ks < 4; ++ks) {
            const float4 e0 = *(const float4*)(er + ks * 32);
            const float4 e1 = *(const float4*)(er + ks * 32 + 4);
            bf16x8 a;
            a[0] = f2bf(e0.x); a[1] = f2bf(e0.y); a[2] = f2bf(e0.z); a[3] = f2bf(e0.w);
            a[4] = f2bf(e1.x); a[5] = f2bf(e1.y); a[6] = f2bf(e1.z); a[7] = f2bf(e1.w);
            af[ks] = a;
        }
        f32x4 acc[4];
#pragma unroll
        for (int n = 0; n < 4; ++n) { f32x4 c = {bv[n], bv[n], bv[n], bv[n]}; acc[n] = c; }
#pragma unroll
        for (int ks = 0; ks < 4; ++ks)
#pragma unroll
            for (int n = 0; n < 4; ++n)
                acc[n] = __builtin_amdgcn_mfma_f32_16x16x32_bf16(af[ks], wf[n][ks], acc[n], 0, 0, 0);
        // pack: slot = reg*4 + n
        unsigned int u[8];
#pragma unroll
        for (int reg = 0; reg < 4; ++reg) {
            u[reg * 2]     = (unsigned int)f2bf(acc[0][reg]) | ((unsigned int)f2bf(acc[1][reg]) << 16);
            u[reg * 2 + 1] = (unsigned int)f2bf(acc[2][reg]) | ((unsigned int)f2bf(acc[3][reg]) << 16);
        }
        unsigned int* op = (unsigned int*)xw_frag
                         + ((((size_t)dbg * 1024 + t0 + tt) * 4 + cw) * 64 + l) * 8;
        *(uint4*)op       = make_uint4(u[0], u[1], u[2], u[3]);
        *(uint4*)(op + 4) = make_uint4(u[4], u[5], u[6], u[7]);
    }
}

// ---------------- K2: MFMA-batched masked LSTM recurrence ----------------
// 8 blocks x 512 threads (8 waves = 2/SIMD). Polynomial activations with
// wave-uniform exact fallback; prefetch via raw pointer increments.
__global__ __launch_bounds__(512, 1) void k_rec(
    const __hip_bfloat16* __restrict__ xw_frag,
    const __hip_bfloat16* __restrict__ u_frag,
    const unsigned char* __restrict__ mask_ws,
    __hip_bfloat16* __restrict__ bi_t) {
    const int bid = blockIdx.x;
    const int d = bid >> 2, bg = bid & 3;
    const int tid = threadIdx.x, wf = tid >> 6, l = tid & 63;
    const int cw = wf >> 1, p = wf & 1;

    bf16x8 bfr[4][2];
    {
        const bf16x8* up = (const bf16x8*)(u_frag + (size_t)(d * 256 + cw * 64 + l) * 64);
#pragma unroll
        for (int n = 0; n < 4; ++n)
#pragma unroll
            for (int kc = 0; kc < 2; ++kc) bfr[n][kc] = up[n * 2 + kc];
    }

    __shared__ __align__(16) unsigned short hbuf[2][1024];
    for (int i = tid; i < 2048; i += 512) hbuf[0][i] = 0;
    __syncthreads();

    const int arow = l & 15;
    const int sw = ((arow >> 2) & 3) << 1;
    const int aoff0 = arow * 128 + (((l >> 4)     ^ sw) & 7) * 16;
    const int aoff1 = arow * 128 + (((4 + (l >> 4)) ^ sw) & 7) * 16;
    const int wch = ((2 * cw + ((l & 15) >> 3)) ^ ((l >> 4) << 1)) & 7;
    const int base_w = (l >> 4) * 512 + wch * 16 + (l & 7) * 2;
    const int woff0 = base_w + (2 * p + 0) * 128;
    const int woff1 = base_w + (2 * p + 1) * 128;

    unsigned short* bt_u = (unsigned short*)bi_t;
    const size_t bt0 = ((size_t)((bg * 16 + 4 * (l >> 4) + 2 * p) * 128
                                 + d * 64 + 16 * cw + (l & 15))) << 10;
    const size_t bt1 = bt0 + (128ull << 10);

    float c_st0 = 0.f, c_st1 = 0.f, h_st0 = 0.f, h_st1 = 0.f;

    const char* xbase = (const char*)xw_frag
                      + ((size_t)(d * 4 + bg) * 1024) * 8192 + (cw * 64 + l) * 32 + p * 16;
    const unsigned char* mbase = mask_ws + ((l >> 4) << 2);
    const int time0 = d ? 1023 : 0;
    const ptrdiff_t xstep = d ? -8192 : 8192;
    const ptrdiff_t mstep = d ? -64 : 64;

    const char* xpf = xbase + (ptrdiff_t)time0 * 8192;
    const unsigned char* mpf = mbase + (ptrdiff_t)time0 * 64;

    uint4 px[2]; unsigned int pmk[2];
#pragma unroll
    for (int j = 0; j < 2; ++j) {
        px[j]  = *(const uint4*)xpf;
        pmk[j] = *(const unsigned int*)mpf;
        xpf += xstep; mpf += mstep;
    }

    unsigned short h4a[4], h4b[4];
    const int shift0 = 16 * p;
    const int shift1 = 16 * p + 8;

    for (int tb = 0; tb < 1024; tb += 4) {
#pragma unroll
        for (int j = 0; j < 4; ++j) {
            const int t = tb + j;
            const uint4 cx = px[j & 1];
            const unsigned int cm = pmk[j & 1];
            // prefetch cursor (over-reads past the sequence land in ws, unused)
            px[j & 1]  = *(const uint4*)xpf;
            pmk[j & 1] = *(const unsigned int*)mpf;
            xpf += xstep; mpf += mstep;

            const char* hb = (const char*)(hbuf[0] + (t & 1) * 1024);
            const bf16x8 a0 = *(const bf16x8*)(hb + aoff0);
            const bf16x8 a1 = *(const bf16x8*)(hb + aoff1);
            float z[8];
            {
                const unsigned int du[4] = {cx.x, cx.y, cx.z, cx.w};
#pragma unroll
                for (int q = 0; q < 4; ++q) {
                    z[2 * q]     = __builtin_bit_cast(float, du[q] << 16);
                    z[2 * q + 1] = __builtin_bit_cast(float, du[q] & 0xffff0000u);
                }
            }
            f32x4 acc[4];
#pragma unroll
            for (int n = 0; n < 4; ++n) {
                f32x4 ci = {z[n], z[4 + n], z[n], z[4 + n]};  // valid at regs {2p,2p+1}
                ci = __builtin_amdgcn_mfma_f32_16x16x32_bf16(a0, bfr[n][0], ci, 0, 0, 0);
                acc[n] = __builtin_amdgcn_mfma_f32_16x16x32_bf16(a1, bfr[n][1], ci, 0, 0, 0);
            }
            unsigned short* hw = hbuf[0] + ((t + 1) & 1) * 1024;
#pragma unroll
            for (int rl = 0; rl < 2; ++rl) {
                const float zi = p ? acc[0][2 + rl] : acc[0][rl];
                const float zf = p ? acc[1][2 + rl] : acc[1][rl];
                const float zg = p ? acc[2][2 + rl] : acc[2][rl];
                const float zo = p ? acc[3][2 + rl] : acc[3][rl];
                const float c_st = rl ? c_st1 : c_st0;
                const float h_st = rl ? h_st1 : h_st0;
                // polynomial fast path (|z|,|c| <= 0.2: abs err < 5e-5)
                float iv = fmaf(zi, fmaf(zi * zi, -1.f / 48.f, 0.25f), 0.5f);
                float fv = fmaf(zf, fmaf(zf * zf, -1.f / 48.f, 0.25f), 0.5f);
                float ov = fmaf(zo, fmaf(zo * zo, -1.f / 48.f, 0.25f), 0.5f);
                const float zg2 = zg * zg;
                float tg = zg * fmaf(zg2, fmaf(zg2, 2.f / 15.f, -1.f / 3.f), 1.f);
                float cn = fmaf(fv, c_st, iv * tg);
                const float mz = fmaxf(fmaxf(fabsf(zi), fabsf(zf)),
                                       fmaxf(fabsf(zg), fmaxf(fabsf(zo), fabsf(cn))));
                float th;
                if (__any(mz > 0.2f)) {          // wave-uniform exact fallback
                    iv = sig_exact(zi); fv = sig_exact(zf); ov = sig_exact(zo);
                    tg = tanh_exact(zg);
                    cn = fmaf(fv, c_st, iv * tg);
                    th = tanh_exact(cn);
                } else {
                    const float cn2 = cn * cn;
                    th = cn * fmaf(cn2, fmaf(cn2, 2.f / 15.f, -1.f / 3.f), 1.f);
                }
                const float hn = ov * th;
                const bool m = (cm >> (rl ? shift1 : shift0)) & 1u;
                const float h2 = m ? hn : h_st;
                if (rl) { c_st1 = m ? cn : c_st1; h_st1 = h2; }
                else    { c_st0 = m ? cn : c_st0; h_st0 = h2; }
                const unsigned short hb16 = f2bf(h2);
                *(unsigned short*)((char*)hw + (rl ? woff1 : woff0)) = hb16;
                if (rl) h4b[j] = hb16; else h4a[j] = hb16;
            }
            if (j == 3) {
                uint2 ua, ub;
                int stime;
                if (d == 0) {
                    ua.x = (unsigned int)h4a[0] | ((unsigned int)h4a[1] << 16);
                    ua.y = (unsigned int)h4a[2] | ((unsigned int)h4a[3] << 16);
                    ub.x = (unsigned int)h4b[0] | ((unsigned int)h4b[1] << 16);
                    ub.y = (unsigned int)h4b[2] | ((unsigned int)h4b[3] << 16);
                    stime = tb;
                } else {
                    ua.x = (unsigned int)h4a[3] | ((unsigned int)h4a[2] << 16);
                    ua.y = (unsigned int)h4a[1] | ((unsigned int)h4a[0] << 16);
                    ub.x = (unsigned int)h4b[3] | ((unsigned int)h4b[2] << 16);
                    ub.y = (unsigned int)h4b[1] | ((unsigned int)h4b[0] << 16);
                    stime = 1020 - tb;
                }
                *(uint2*)(bt_u + bt0 + stime) = ua;
                *(uint2*)(bt_u + bt1 + stime) = ub;
            }
            asm volatile("s_waitcnt lgkmcnt(0)" ::: "memory");
            __builtin_amdgcn_s_barrier();
        }
    }
}

// ---------------- K3: event_logits (reads transposed bi_t) ----------------
__global__ __launch_bounds__(1024) void k_logits(
    const __hip_bfloat16* __restrict__ bi_t, const float* __restrict__ Wt,
    const float* __restrict__ bt, float* __restrict__ out) {
    const int tid = threadIdx.x;
    const int b = tid >> 4, cls = tid & 15;
    const unsigned short* btu = (const unsigned short*)bi_t;
    float acc = bt[cls];
    for (int k = 0; k < 128; ++k)
        acc = fmaf(bf2f(btu[(((size_t)b * 128 + k) << 10) + 1023]), Wt[k * 16 + cls], acc);
    out[tid] = 1.f / (1.f + __expf(-acc));
}

// ---------------- K4: expert-dedup einsum, list-driven scatter ----------------
__global__ __launch_bounds__(256) void k_args(
    const __hip_bfloat16* __restrict__ bi_t,
    const float* __restrict__ ev_table, const int* __restrict__ evt,
    const float* __restrict__ W_arg, const float* __restrict__ b_arg,
    const int* __restrict__ elist,
    float* __restrict__ out_args) {
    const int e = blockIdx.x;
    const int cnt = elist[e * 65];
    if (cnt == 0) return;
    const int rowbase = blockIdx.y * 64;
    const int cc = rowbase >> 10, sbase = rowbase & 1023;
    __shared__ float feat[64][169];
    __shared__ __align__(16) float w[1280];
    __shared__ float partial[4][64][8];
    __shared__ int   bl_l[64];
    __shared__ float bg[8];
    const int tid = threadIdx.x;
    for (int i = tid; i < 1280; i += 256) w[i] = W_arg[(size_t)e * 1280 + i];
    if (tid < cnt) bl_l[tid] = elist[e * 65 + 1 + tid];
    if (tid < 8)  bg[tid] = b_arg[e * 8 + tid];
    const unsigned short* btu = (const unsigned short*)bi_t;
    for (int i = tid; i < 64 * 128; i += 256) {
        const int k = i >> 6, r = i & 63;
        feat[r][k] = bf2f(btu[(((size_t)cc * 128 + k) << 10) + sbase + r]);
    }
    {
        const int ie = evt[cc];
        const float* evrow = ev_table + (size_t)ie * 32;
        for (int i = tid; i < 64 * 32; i += 256) {
            const int r = i >> 5, k = i & 31;
            feat[r][128 + k] = evrow[k];
        }
    }
    __syncthreads();
    const int r = tid & 63, seg = tid >> 6;
    float acc[8];
#pragma unroll
    for (int a = 0; a < 8; ++a) acc[a] = 0.f;
    const int f0 = seg * 40;
    for (int f = f0; f < f0 + 40; ++f) {
        const float fv = feat[r][f];
        const float4 w0 = *reinterpret_cast<const float4*>(&w[f * 8]);
        const float4 w1 = *reinterpret_cast<const float4*>(&w[f * 8 + 4]);
        acc[0] = fmaf(fv, w0.x, acc[0]);
        acc[1] = fmaf(fv, w0.y, acc[1]);
        acc[2] = fmaf(fv, w0.z, acc[2]);
        acc[3] = fmaf(fv, w0.w, acc[3]);
        acc[4] = fmaf(fv, w1.x, acc[4]);
        acc[5] = fmaf(fv, w1.y, acc[5]);
        acc[6] = fmaf(fv, w1.z, acc[6]);
        acc[7] = fmaf(fv, w1.w, acc[7]);
    }
#pragma unroll
    for (int a = 0; a < 8; ++a) partial[seg][r][a] = acc[a];
    __syncthreads();
    for (int o = tid; o < 512; o += 256) {
        const int rr = o >> 3, a = o & 7;
        const float v = bg[a] + partial[0][rr][a] + partial[1][rr][a]
                              + partial[2][rr][a] + partial[3][rr][a];
        const size_t base = ((size_t)(rowbase + rr)) * 8 + a;
        for (int j = 0; j < cnt; ++j)
            out_args[((size_t)bl_l[j] << 19) + base] = v;
    }
}

// ---------------- K5: mask ----------------
__global__ __launch_bounds__(256) void k_mask(const int* __restrict__ inputs,
                                              float* __restrict__ om,
                                              unsigned char* __restrict__ mws) {
    const int i = blockIdx.x * 256 + threadIdx.x;
    const int b = i >> 10, s = i & 1023;
    const int nz = (inputs[i] != 0) ? 1 : 0;
    om[i] = (float)nz;
    mws[s * 64 + b] = (unsigned char)nz;
}

extern "C" void kernel_launch(void* const* d_in, const int* in_sizes, int n_in,
                              void* d_out, int out_size, void* d_ws, size_t ws_size,
                              hipStream_t stream) {
    const int*   inputs = (const int*)d_in[0];
    const int*   evt    = (const int*)d_in[1];
    const float* embed  = (const float*)d_in[2];
    const float* Wf     = (const float*)d_in[3];
    const float* Uf     = (const float*)d_in[4];
    const float* bf_    = (const float*)d_in[5];
    const float* Wb     = (const float*)d_in[6];
    const float* Ub     = (const float*)d_in[7];
    const float* bb_    = (const float*)d_in[8];
    const float* evtab  = (const float*)d_in[9];
    const float* Wt     = (const float*)d_in[10];
    const float* bt     = (const float*)d_in[11];
    const float* W_arg  = (const float*)d_in[12];
    const float* b_arg  = (const float*)d_in[13];

    float* out        = (float*)d_out;
    float* out_logits = out;
    float* out_args   = out + 1024;
    float* out_mask   = out + 1024 + 33554432;

    __hip_bfloat16* xw_frag = (__hip_bfloat16*)d_ws;
    __hip_bfloat16* bi_t    = xw_frag + XW_ELEMS;
    __hip_bfloat16* u_frag  = bi_t + BI_ELEMS;
    __hip_bfloat16* w_frag  = u_frag + U_ELEMS;
    unsigned char*  mask_ws = (unsigned char*)(w_frag + W_ELEMS);
    int*            elist   = (int*)(mask_ws + 65536);

    k_uprep <<<dim3(2),        256, 0, stream>>>(Uf, Ub, u_frag);
    k_wprep <<<dim3(2),        256, 0, stream>>>(Wf, Wb, w_frag);
    k_elist <<<dim3(1),         64, 0, stream>>>(evt, elist);
    k_mask  <<<dim3(256),      256, 0, stream>>>(inputs, out_mask, mask_ws);
    k_xw    <<<dim3(128, 8),   256, 0, stream>>>(inputs, embed, bf_, bb_, w_frag, xw_frag);
    k_rec   <<<dim3(8),        512, 0, stream>>>(xw_frag, u_frag, mask_ws, bi_t);
    k_logits<<<dim3(1),       1024, 0, stream>>>(bi_t, Wt, bt, out_logits);
    k_args  <<<dim3(15, 1024), 256, 0, stream>>>(bi_t, evtab, evt, W_arg, b_arg, elist, out_args);
}